// Round 24
// baseline (178.934 us; speedup 1.0000x reference)
//
#include <hip/hip_runtime.h>
#include <math.h>

#define EPSV 0.1f
#define MAX_ITER 10
constexpr int NB       = 16;
constexpr int IN_SIZE  = 1024;
constexpr int IN_DIM   = 1024;
constexpr int HEADS    = 4;
constexpr int OUT_SIZE = 128;
constexpr int OUT_DIM  = 1024;

typedef __attribute__((ext_vector_type(8))) _Float16 f16x8;
typedef __attribute__((ext_vector_type(4))) float f32x4;

__device__ __forceinline__ unsigned cvth2(float lo, float hi) {
    _Float16 a = (_Float16)lo, b = (_Float16)hi;
    unsigned short ua = *(unsigned short*)&a, ub = *(unsigned short*)&b;
    return (unsigned)ua | ((unsigned)ub << 16);
}
__device__ __forceinline__ unsigned short cvth1(float f) {
    _Float16 a = (_Float16)f;
    return *(unsigned short*)&a;
}
__device__ __forceinline__ unsigned short bf16rne(float f) {
    unsigned a = __float_as_uint(f);
    return (unsigned short)((a + 0x7fffu + ((a >> 16) & 1u)) >> 16);
}
// async global->LDS, 16 B per lane: HW writes lane l at ldsbase + l*16.
__device__ __forceinline__ void glds16(const void* g, void* l) {
    __builtin_amdgcn_global_load_lds(
        (const __attribute__((address_space(1))) unsigned int*)g,
        (__attribute__((address_space(3))) unsigned int*)l, 16, 0, 0);
}

// ---------------------------------------------------------------------------
// MFMA fp16 GEMM, M fixed 128, double-buffered. A fp16 glds (linear LDS
// [rows][32]); B fp16 glds or fp32 reg-staged (padded 40).
// CMODE: 1 = fp16 store, 2 = f32+bias+relu
// HMAP : head-major tile remap (z&15=n, z>>4=m, b=n*4+m).
// ---------------------------------------------------------------------------
template<bool B_F32, int CMODE, int NF, bool SWAP, bool HMAP>
__global__ __launch_bounds__(256)
void mfma_gemm(const void* __restrict__ Ap, const void* __restrict__ Bp,
               const float* __restrict__ bias, void* __restrict__ Cp,
               int K, int lda, int ldb, int ldc, int div,
               long AsN, long AsM, long BsN, long BsM, long CsN, long CsM,
               float alpha)
{
    constexpr int BN   = NF * 32;
    constexpr int BSTR = B_F32 ? 40 : 32;
    const int z  = SWAP ? blockIdx.x : blockIdx.z;
    const int n0 = (SWAP ? blockIdx.z : blockIdx.x) * BN;
    long aoff, boff, coff;
    if (HMAP) {
        const int nn = z & 15, mm = z >> 4, bt = nn * 4 + mm;
        aoff = (long)bt * AsM; boff = (long)nn * BsN; coff = (long)bt * CsM;
    } else {
        aoff = (long)(z / div) * AsN + (long)(z % div) * AsM;
        boff = (long)(z / div) * BsN + (long)(z % div) * BsM;
        coff = (long)(z / div) * CsN + (long)(z % div) * CsM;
    }

    __shared__ short As[2][128 * 32];
    __shared__ short Bs[2][BN * BSTR];

    const int t = threadIdx.x;
    const int lane = t & 63;
    const int w = t >> 6, wr = w >> 1, wc = w & 1;
    const int lrow = lane >> 2, lce = (lane & 3) * 8;

    auto stage = [&](int buf, int k0) {
        const long abase = aoff + k0;
        const long bbase = boff + k0;
        #pragma unroll
        for (int j = 0; j < 2; ++j) {
            const int row0 = (w * 2 + j) * 16;
            glds16((const short*)Ap + abase + (long)(row0 + lrow) * lda + lce,
                   &As[buf][row0 * 32]);
        }
        if (B_F32) {
            #pragma unroll
            for (int itr = 0; itr < BN / 64; ++itr) {
                const int idx = itr * 256 + t;
                const int row = idx >> 2, kq = idx & 3;
                const float* s = (const float*)Bp + bbase + (long)(n0 + row) * ldb + kq * 8;
                const float4 f0 = *(const float4*)s, f1 = *(const float4*)(s + 4);
                uint4 p;
                p.x = cvth2(f0.x, f0.y); p.y = cvth2(f0.z, f0.w);
                p.z = cvth2(f1.x, f1.y); p.w = cvth2(f1.z, f1.w);
                *(uint4*)&Bs[buf][row * BSTR + kq * 8] = p;
            }
        } else {
            #pragma unroll
            for (int j = 0; j < BN / 64; ++j) {
                const int row0 = (w * (BN / 64) + j) * 16;
                glds16((const short*)Bp + bbase + (long)(n0 + row0 + lrow) * ldb + lce,
                       &Bs[buf][row0 * 32]);
            }
        }
    };

    f32x4 acc[4][NF];
    #pragma unroll
    for (int i = 0; i < 4; ++i)
        #pragma unroll
        for (int j = 0; j < NF; ++j) { acc[i][j].x = 0.f; acc[i][j].y = 0.f; acc[i][j].z = 0.f; acc[i][j].w = 0.f; }

    stage(0, 0);
    __syncthreads();
    int cur = 0;

    for (int k0 = 0; k0 < K; k0 += 32) {
        if (k0 + 32 < K) stage(cur ^ 1, k0 + 32);

        f16x8 af[4], bfr[NF];
        #pragma unroll
        for (int mi = 0; mi < 4; ++mi)
            af[mi] = *(const f16x8*)&As[cur][(wr * 64 + mi * 16 + (lane & 15)) * 32 + (lane >> 4) * 8];
        #pragma unroll
        for (int ni = 0; ni < NF; ++ni)
            bfr[ni] = *(const f16x8*)&Bs[cur][(wc * (BN / 2) + ni * 16 + (lane & 15)) * BSTR + (lane >> 4) * 8];
        #pragma unroll
        for (int mi = 0; mi < 4; ++mi)
            #pragma unroll
            for (int ni = 0; ni < NF; ++ni)
                acc[mi][ni] = __builtin_amdgcn_mfma_f32_16x16x32_f16(af[mi], bfr[ni], acc[mi][ni], 0, 0, 0);
        __syncthreads();
        cur ^= 1;
    }

    #pragma unroll
    for (int mi = 0; mi < 4; ++mi) {
        #pragma unroll
        for (int ni = 0; ni < NF; ++ni) {
            #pragma unroll
            for (int j = 0; j < 4; ++j) {
                const int row = wr * 64 + mi * 16 + (lane >> 4) * 4 + j;
                const int col = n0 + wc * (BN / 2) + ni * 16 + (lane & 15);
                float v = acc[mi][ni][j] * alpha;
                if (CMODE == 2) { v += bias[col]; v = fmaxf(v, 0.f); }
                if (CMODE == 2) ((float*)Cp)[coff + (long)row * ldc + col] = v;
                else ((unsigned short*)Cp)[coff + (long)row * ldc + col] = cvth1(v);
            }
        }
    }
}

// ---------------------------------------------------------------------------
// split-K reduce (fp16 partials): out = relu(sum_ks p[ks] + bias), 8/thread.
// ---------------------------------------------------------------------------
__global__ __launch_bounds__(256)
void splitk_reduce(const unsigned short* __restrict__ part,
                   const float* __restrict__ bias, float* __restrict__ out)
{
    const long idx = ((long)blockIdx.x * 256 + threadIdx.x) * 8;
    const int o = (int)(idx & 1023);
    const f16x8 p0 = *(const f16x8*)(part + idx);
    const f16x8 p1 = *(const f16x8*)(part + 2097152 + idx);
    const f16x8 p2 = *(const f16x8*)(part + 2 * 2097152 + idx);
    const f16x8 p3 = *(const f16x8*)(part + 3 * 2097152 + idx);
    const float4 b0 = *(const float4*)(bias + o);
    const float4 b1 = *(const float4*)(bias + o + 4);
    float r[8];
    #pragma unroll
    for (int j = 0; j < 8; ++j) {
        const float bv = j < 4 ? (&b0.x)[j] : (&b1.x)[j - 4];
        r[j] = fmaxf((float)p0[j] + (float)p1[j] + (float)p2[j] + (float)p3[j] + bv, 0.f);
    }
    *(float4*)(out + idx)     = *(float4*)&r[0];
    *(float4*)(out + idx + 4) = *(float4*)&r[4];
}

// ---------------------------------------------------------------------------
__global__ __launch_bounds__(256)
void cvt_f16(const float* __restrict__ in, unsigned short* __restrict__ out)
{
    const long i8 = ((long)blockIdx.x * 256 + threadIdx.x) * 8;
    const float4 f0 = *(const float4*)(in + i8), f1 = *(const float4*)(in + i8 + 4);
    uint4 p;
    p.x = cvth2(f0.x, f0.y); p.y = cvth2(f0.z, f0.w);
    p.z = cvth2(f1.x, f1.y); p.w = cvth2(f1.z, f1.w);
    *(uint4*)(out + i8) = p;
}

// ---------------------------------------------------------------------------
// FUSED gemm1 + sinkhorn: one block per (tile, i-quarter). Grid (64,1,4),
// 512 threads, head-major bx (nn=bx&15, mm=bx>>4). Block computes
// K = 10*otwH . x^T for [128 s][256 i], colmax->Mi (block-local), writes
// ek = bf16(exp(K-Mi)) into LDS (v7 129-dword-stride layout), runs the v7
// sinkhorn iterations in place (4-sibling exchange, siblings on XCD bx%8),
// and writes T fp16 to global. ek/Mi never touch global memory. Also
// produces xT (R22 scheme) from the staged fp16 B tile.
// LDS ~135 KB -> 1 block/CU -> 256-VGPR budget (no spill).
// ---------------------------------------------------------------------------
__global__ __launch_bounds__(512)
void gemm1_sinkhorn(const unsigned short* __restrict__ otwH,
                    const float* __restrict__ x,
                    unsigned short* __restrict__ Tb,
                    unsigned short* __restrict__ xTo,
                    float* __restrict__ xchg, unsigned int* __restrict__ ctr)
{
    const int hm = blockIdx.x;
    const int nn = hm & 15, mm = hm >> 4;
    const int bt = nn * 4 + mm;               // canonical tile index
    const int q  = blockIdx.z;                // i-quarter (256 i)
    const int n0 = q * 256;

    const unsigned short* A = otwH + (long)mm * (OUT_SIZE * IN_DIM);
    const float* B = x + (long)nn * (IN_SIZE * IN_DIM);

    __shared__ short As[2][128 * 32];         // 16 KB
    __shared__ short Bs[2][256 * 40];         // 40 KB
    __shared__ unsigned ekw[128 * 129];       // 66 KB, bf16-pairs stride 129 dw
    __shared__ float part_u[4][256];
    __shared__ float part_v[4][128];
    __shared__ float eu_l[256];
    __shared__ float Mi_s[256];
    __shared__ float v_s[128], ev_s[128];
    __shared__ float colmax[2][256];
    __shared__ float red8[8];
    __shared__ float wg_s;

    const int t = threadIdx.x;
    const int lane = t & 63;
    const int w = t >> 6;                     // 0..7
    const int wr = w >> 2, wc = w & 3;        // 2 x 4 wave grid (128 x 256)
    const int lrow = lane >> 2, lce = (lane & 3) * 8;

    auto stage = [&](int buf, int k0) {
        {   // A: 128 rows x 32 k fp16, 1 glds16 per wave
            const int row0 = w * 16;
            glds16(A + (long)(row0 + lrow) * 1024 + k0 + lce, &As[buf][row0 * 32]);
        }
        #pragma unroll
        for (int itr = 0; itr < 2; ++itr) {   // B: 256 rows x 32 k fp32->fp16
            const int idx = itr * 512 + t;
            const int row = idx >> 2, kq = idx & 3;
            const float* s = B + (long)(n0 + row) * 1024 + k0 + kq * 8;
            const float4 f0 = *(const float4*)s, f1 = *(const float4*)(s + 4);
            uint4 p;
            p.x = cvth2(f0.x, f0.y); p.y = cvth2(f0.z, f0.w);
            p.z = cvth2(f1.x, f1.y); p.w = cvth2(f1.z, f1.w);
            *(uint4*)&Bs[buf][row * 40 + kq * 8] = p;
        }
    };

    f32x4 acc[4][4];
    #pragma unroll
    for (int i = 0; i < 4; ++i)
        #pragma unroll
        for (int j = 0; j < 4; ++j) { acc[i][j].x = 0.f; acc[i][j].y = 0.f; acc[i][j].z = 0.f; acc[i][j].w = 0.f; }

    stage(0, 0);
    __syncthreads();
    int cur = 0;

    unsigned short* xTn = xTo + (long)nn * (IN_SIZE * IN_DIM);

    for (int k0 = 0; k0 < 1024; k0 += 32) {
        if (k0 + 32 < 1024) stage(cur ^ 1, k0 + 32);

        f16x8 af[4], bfr[4];
        #pragma unroll
        for (int mi = 0; mi < 4; ++mi)
            af[mi] = *(const f16x8*)&As[cur][(wr * 64 + mi * 16 + (lane & 15)) * 32 + (lane >> 4) * 8];
        #pragma unroll
        for (int ni = 0; ni < 4; ++ni)
            bfr[ni] = *(const f16x8*)&Bs[cur][(wc * 64 + ni * 16 + (lane & 15)) * 40 + (lane >> 4) * 8];
        #pragma unroll
        for (int mi = 0; mi < 4; ++mi)
            #pragma unroll
            for (int ni = 0; ni < 4; ++ni)
                acc[mi][ni] = __builtin_amdgcn_mfma_f32_16x16x32_f16(af[mi], bfr[ni], acc[mi][ni], 0, 0, 0);

        // ---- xT producer: this head's d-range (8 of 32 k-steps) ----
        if ((k0 >> 8) == mm) {
            const int dl = t & 31;            // d within k-step
            const int ig = (t >> 5) * 16;     // i-group base (16 groups of 16)
            unsigned short tmp[16];
            #pragma unroll
            for (int j = 0; j < 16; ++j)
                tmp[j] = (unsigned short)Bs[cur][(ig + j) * 40 + dl];
            unsigned short* dst = xTn + (long)(k0 + dl) * IN_SIZE + n0 + ig;
            *(uint4*)dst       = *(uint4*)&tmp[0];
            *(uint4*)(dst + 8) = *(uint4*)&tmp[8];
        }
        __syncthreads();
        cur ^= 1;
    }

    // ---- colmax over s (rows) for each of 256 cols ----
    {
        float lm[4];
        #pragma unroll
        for (int ni = 0; ni < 4; ++ni) {
            float mx = -INFINITY;
            #pragma unroll
            for (int mi = 0; mi < 4; ++mi)
                #pragma unroll
                for (int j = 0; j < 4; ++j) mx = fmaxf(mx, acc[mi][ni][j]);
            mx *= 10.0f;
            mx = fmaxf(mx, __shfl_xor(mx, 16, 64));
            mx = fmaxf(mx, __shfl_xor(mx, 32, 64));
            lm[ni] = mx;
        }
        if ((lane >> 4) == 0) {
            #pragma unroll
            for (int ni = 0; ni < 4; ++ni)
                colmax[wr][wc * 64 + ni * 16 + lane] = lm[ni];
        }
    }
    __syncthreads();
    if (t < 256) Mi_s[t] = fmaxf(colmax[0][t], colmax[1][t]);
    if (t < 128) { v_s[t] = 0.f; ev_s[t] = 1.0f; }
    __syncthreads();

    // ---- ek = bf16(exp(10*acc - Mi)) -> LDS (b16 half-writes) ----
    {
        unsigned short* ek16 = (unsigned short*)ekw;
        #pragma unroll
        for (int ni = 0; ni < 4; ++ni) {
            const int col = wc * 64 + ni * 16 + (lane & 15);
            const float mi_c = Mi_s[col];
            #pragma unroll
            for (int mi = 0; mi < 4; ++mi) {
                #pragma unroll
                for (int j = 0; j < 4; ++j) {
                    const int row = wr * 64 + mi * 16 + (lane >> 4) * 4 + j;
                    ek16[row * 258 + col] = bf16rne(__expf(fmaf(acc[mi][ni][j], 10.f, -mi_c)));
                }
            }
        }
    }
    float u_reg = 0.f, w_t = 0.f;
    const float mi_t = (t < 256) ? Mi_s[t] : 0.f;
    __syncthreads();

    const float A0 = -2.0794415416798357f;   // log(128/1024)
    float vmx = 0.f;

    for (int it = 0; it < MAX_ITER; ++it) {
        // ---- u-pass: 4 s-groups of 32, 128 i-pairs ----
        {
            const int p = t & 127, sq = t >> 7;
            float s0 = 0.f, s1 = 0.f;
            #pragma unroll
            for (int j = 0; j < 32; ++j) {
                const int s = sq * 32 + j;
                const unsigned e = ekw[s * 129 + p];
                const float evv = ev_s[s];
                s0 = fmaf(__uint_as_float(e << 16),          evv, s0);
                s1 = fmaf(__uint_as_float(e & 0xffff0000u),  evv, s1);
            }
            part_u[sq][2 * p]     = s0;
            part_u[sq][2 * p + 1] = s1;
        }
        __syncthreads();

        // ---- u update (t<256 owns i = t), local wmx ----
        if (t < 256) {
            const float S = part_u[0][t] + part_u[1][t] + part_u[2][t] + part_u[3][t];
            const float un = A0 - u_reg - mi_t - vmx - __logf(S);
            u_reg = un;
            w_t = mi_t + un;
            float wl = w_t;
            #pragma unroll
            for (int m = 1; m < 64; m <<= 1) wl = fmaxf(wl, __shfl_xor(wl, m, 64));
            if (lane == 0) red8[4 + w] = wl;   // waves 0..3
        }
        __syncthreads();
        const float wmx_l = fmaxf(fmaxf(red8[4], red8[5]), fmaxf(red8[6], red8[7]));
        if (t < 256) eu_l[t] = __expf(w_t - wmx_l);
        __syncthreads();

        // ---- v-pass: 4 i-groups of 32 pairs ----
        {
            const int s = t & 127, g = t >> 7;
            float acc2 = 0.f;
            #pragma unroll
            for (int j = 0; j < 32; ++j) {
                const int p = 32 * g + j;
                const unsigned e = ekw[s * 129 + p];
                const float2 eup = *(const float2*)&eu_l[2 * p];
                acc2 = fmaf(__uint_as_float(e << 16),         eup.x, acc2);
                acc2 = fmaf(__uint_as_float(e & 0xffff0000u), eup.y, acc2);
            }
            part_v[g][s] = acc2;
        }
        __syncthreads();

        // ---- publish, arrive, relaxed-spin (4 siblings, same XCD) ----
        float* slot = xchg + ((long)(bt * MAX_ITER + it) * 4 + q) * 160;
        if (t < 128) {
            const float cp_l = part_v[0][t] + part_v[1][t] + part_v[2][t] + part_v[3][t];
            __hip_atomic_store(slot + t, cp_l, __ATOMIC_RELAXED, __HIP_MEMORY_SCOPE_AGENT);
        }
        if (t == 0)
            __hip_atomic_store(slot + 128, wmx_l, __ATOMIC_RELAXED, __HIP_MEMORY_SCOPE_AGENT);
        __syncthreads();
        if (t == 0) {
            unsigned int* c = ctr + bt * MAX_ITER + it;
            __hip_atomic_fetch_add(c, 1u, __ATOMIC_RELEASE, __HIP_MEMORY_SCOPE_AGENT);
            while (__hip_atomic_load(c, __ATOMIC_RELAXED, __HIP_MEMORY_SCOPE_AGENT) < 4u) {}
            (void)__hip_atomic_load(c, __ATOMIC_ACQUIRE, __HIP_MEMORY_SCOPE_AGENT);
        }
        __syncthreads();

        // ---- combine (identical in all 4 siblings) ----
        if (t < 128) {
            float* base = xchg + (long)(bt * MAX_ITER + it) * 4 * 160;
            const float w0 = __hip_atomic_load(base + 0 * 160 + 128, __ATOMIC_RELAXED, __HIP_MEMORY_SCOPE_AGENT);
            const float w1 = __hip_atomic_load(base + 1 * 160 + 128, __ATOMIC_RELAXED, __HIP_MEMORY_SCOPE_AGENT);
            const float w2 = __hip_atomic_load(base + 2 * 160 + 128, __ATOMIC_RELAXED, __HIP_MEMORY_SCOPE_AGENT);
            const float w3 = __hip_atomic_load(base + 3 * 160 + 128, __ATOMIC_RELAXED, __HIP_MEMORY_SCOPE_AGENT);
            const float wg = fmaxf(fmaxf(w0, w1), fmaxf(w2, w3));
            const float c0 = __hip_atomic_load(base + 0 * 160 + t, __ATOMIC_RELAXED, __HIP_MEMORY_SCOPE_AGENT);
            const float c1 = __hip_atomic_load(base + 1 * 160 + t, __ATOMIC_RELAXED, __HIP_MEMORY_SCOPE_AGENT);
            const float c2 = __hip_atomic_load(base + 2 * 160 + t, __ATOMIC_RELAXED, __HIP_MEMORY_SCOPE_AGENT);
            const float c3 = __hip_atomic_load(base + 3 * 160 + t, __ATOMIC_RELAXED, __HIP_MEMORY_SCOPE_AGENT);
            const float cp = c0 * __expf(w0 - wg) + c1 * __expf(w1 - wg)
                           + c2 * __expf(w2 - wg) + c3 * __expf(w3 - wg);
            const float vn = -v_s[t] - wg - __logf(cp);
            v_s[t] = vn;
            if (t == 0) wg_s = wg;
            float xv = vn;
            #pragma unroll
            for (int m = 1; m < 64; m <<= 1) xv = fmaxf(xv, __shfl_xor(xv, m, 64));
            if (lane == 0) red8[w] = xv;       // waves 0..1
        }
        __syncthreads();
        vmx = fmaxf(red8[0], red8[1]);
        if (t < 128) ev_s[t] = __expf(v_s[t] - vmx);
        __syncthreads();
    }

    // ---- T fp16 write: T = ek * eu[i] * ecv[s] ----
    const float wg = wg_s;
    if (t < 256) eu_l[t] = __expf(w_t - wg);
    if (t < 128) ev_s[t] = __expf(v_s[t] + wg);
    __syncthreads();
    unsigned short* To = Tb + (long)bt * 131072 + q * 256;
    #pragma unroll
    for (int j = 0; j < 32; ++j) {
        const int idx = t + 512 * j;          // 0..16383 pairs
        const int s  = idx >> 7;
        const int ip = idx & 127;
        const unsigned e = ekw[s * 129 + ip];
        const float2 eup = *(const float2*)&eu_l[2 * ip];
        const float ec = ev_s[s];
        const float lo = __uint_as_float(e << 16)         * eup.x * ec;
        const float hi = __uint_as_float(e & 0xffff0000u) * eup.y * ec;
        *(unsigned*)(To + (long)s * 1024 + ip * 2) = cvth2(lo, hi);
    }
}

// ---------------------------------------------------------------------------
extern "C" void kernel_launch(void* const* d_in, const int* in_sizes, int n_in,
                              void* d_out, int out_size, void* d_ws, size_t ws_size,
                              hipStream_t stream)
{
    const float* x     = (const float*)d_in[0];   // [16][1024][1024]
    const float* otw   = (const float*)d_in[1];   // [4][128][1024]
    const float* lin_w = (const float*)d_in[2];   // [1024][4096]
    const float* lin_b = (const float*)d_in[3];   // [1024]
    float* out = (float*)d_out;                   // [16][128][1024] fp32 (8 MB)

    // ws (64 MB): [0,32M) xT fp16 (dead after GEMM2 -> fp16 split-K partials)
    //             [32M,48M) T fp16 (written by fused kernel); [48M,64M) feat
    unsigned short* xT   = (unsigned short*)d_ws;
    unsigned short* Tb   = xT + 16777216;
    unsigned short* feat = Tb + 8388608;
    unsigned short* partial = (unsigned short*)d_ws;  // [4][16][128][1024] fp16
    // d_out scratch (fully overwritten by splitk_reduce):
    //   xchg [64][10][4][160] f32 @131072 ; ctr [64][10] u32 @655360 ;
    //   otwH fp16 @786432
    float* base = (float*)d_out;
    float* xchg = base + 131072;
    unsigned int* ctrB = (unsigned int*)(base + 655360);
    unsigned short* otwH = (unsigned short*)(base + 786432);

    hipMemsetAsync(ctrB, 0, 64 * MAX_ITER * sizeof(unsigned int), stream);

    // -1) otw -> fp16 (tiny)
    cvt_f16<<<dim3(256), 256, 0, stream>>>(otw, otwH);

    // 1+2) fused K-GEMM + colmax + exp + sinkhorn + T + xT producer
    gemm1_sinkhorn<<<dim3(64, 1, 4), 512, 0, stream>>>(
        otwH, x, Tb, xT, xchg, ctrB);

    // 3) feat = T . xT^T: NF=2, grid (64,1,16) = 4 blocks/CU, HMAP
    mfma_gemm<false, 1, 2, true, true><<<dim3(64, 1, 16), 256, 0, stream>>>(
        Tb, xT, nullptr, feat,
        1024, 1024, 1024, 1024, 4,
        0, 131072, 1048576, 0, 0, 131072, 1.0f);

    // 4) split-K x4 GEMM3 -> fp16 partials (CMODE 1)
    mfma_gemm<true, 1, 2, false, false><<<dim3(16, 1, 64), 256, 0, stream>>>(
        feat, lin_w, nullptr, partial,
        1024, 1024, 4096, 1024, 16,
        131072, 524288, 1024, 0, 2097152, 131072, 1.0f);

    // 5) out = relu(sum_ks partial + bias)
    splitk_reduce<<<dim3(1024), 256, 0, stream>>>(partial, lin_b, out);
}

// Round 25
// 174.977 us; speedup vs baseline: 1.0226x; 1.0226x over previous
//
#include <hip/hip_runtime.h>
#include <math.h>

#define EPSV 0.1f
#define MAX_ITER 10
constexpr int NB       = 16;
constexpr int IN_SIZE  = 1024;
constexpr int IN_DIM   = 1024;
constexpr int HEADS    = 4;
constexpr int OUT_SIZE = 128;
constexpr int OUT_DIM  = 1024;

typedef __attribute__((ext_vector_type(8))) _Float16 f16x8;
typedef __attribute__((ext_vector_type(4))) float f32x4;

__device__ __forceinline__ unsigned cvth2(float lo, float hi) {
    _Float16 a = (_Float16)lo, b = (_Float16)hi;
    unsigned short ua = *(unsigned short*)&a, ub = *(unsigned short*)&b;
    return (unsigned)ua | ((unsigned)ub << 16);
}
__device__ __forceinline__ unsigned short cvth1(float f) {
    _Float16 a = (_Float16)f;
    return *(unsigned short*)&a;
}
__device__ __forceinline__ unsigned short bf16rne(float f) {
    unsigned a = __float_as_uint(f);
    return (unsigned short)((a + 0x7fffu + ((a >> 16) & 1u)) >> 16);
}
// async global->LDS, 16 B per lane: HW writes lane l at ldsbase + l*16.
__device__ __forceinline__ void glds16(const void* g, void* l) {
    __builtin_amdgcn_global_load_lds(
        (const __attribute__((address_space(1))) unsigned int*)g,
        (__attribute__((address_space(3))) unsigned int*)l, 16, 0, 0);
}

// ---------------------------------------------------------------------------
// MFMA fp16 GEMM, M fixed 128, double-buffered. A fp16 glds (linear LDS
// [rows][32]); B fp16 glds or fp32 reg-staged (padded 40).
// CMODE: 1 = fp16 store, 2 = f32+bias+relu
// HMAP : head-major tile remap (z&15=n, z>>4=m, b=n*4+m) -> all 4 heads of
//        batch n on XCD n%8: shared B slab fetched once per XCD.
// ---------------------------------------------------------------------------
template<bool B_F32, int CMODE, int NF, bool SWAP, bool HMAP>
__global__ __launch_bounds__(256)
void mfma_gemm(const void* __restrict__ Ap, const void* __restrict__ Bp,
               const float* __restrict__ bias, void* __restrict__ Cp,
               int K, int lda, int ldb, int ldc, int div,
               long AsN, long AsM, long BsN, long BsM, long CsN, long CsM,
               float alpha)
{
    constexpr int BN   = NF * 32;
    constexpr int BSTR = B_F32 ? 40 : 32;   // B LDS row stride (elems)
    const int z  = SWAP ? blockIdx.x : blockIdx.z;
    const int n0 = (SWAP ? blockIdx.z : blockIdx.x) * BN;
    long aoff, boff, coff;
    if (HMAP) {
        const int nn = z & 15, mm = z >> 4, bt = nn * 4 + mm;
        aoff = (long)bt * AsM; boff = (long)nn * BsN; coff = (long)bt * CsM;
    } else {
        aoff = (long)(z / div) * AsN + (long)(z % div) * AsM;
        boff = (long)(z / div) * BsN + (long)(z % div) * BsM;
        coff = (long)(z / div) * CsN + (long)(z % div) * CsM;
    }

    __shared__ short As[2][128 * 32];
    __shared__ short Bs[2][BN * BSTR];

    const int t = threadIdx.x;
    const int lane = t & 63;
    const int w = t >> 6, wr = w >> 1, wc = w & 1;
    const int lrow = lane >> 2, lce = (lane & 3) * 8;   // glds lane mapping

    auto stage = [&](int buf, int k0) {
        const long abase = aoff + k0;
        const long bbase = boff + k0;
        #pragma unroll
        for (int j = 0; j < 2; ++j) {
            const int row0 = (w * 2 + j) * 16;
            glds16((const short*)Ap + abase + (long)(row0 + lrow) * lda + lce,
                   &As[buf][row0 * 32]);
        }
        if (B_F32) {
            #pragma unroll
            for (int itr = 0; itr < BN / 64; ++itr) {
                const int idx = itr * 256 + t;
                const int row = idx >> 2, kq = idx & 3;
                const float* s = (const float*)Bp + bbase + (long)(n0 + row) * ldb + kq * 8;
                const float4 f0 = *(const float4*)s, f1 = *(const float4*)(s + 4);
                uint4 p;
                p.x = cvth2(f0.x, f0.y); p.y = cvth2(f0.z, f0.w);
                p.z = cvth2(f1.x, f1.y); p.w = cvth2(f1.z, f1.w);
                *(uint4*)&Bs[buf][row * BSTR + kq * 8] = p;
            }
        } else {
            #pragma unroll
            for (int j = 0; j < BN / 64; ++j) {
                const int row0 = (w * (BN / 64) + j) * 16;
                glds16((const short*)Bp + bbase + (long)(n0 + row0 + lrow) * ldb + lce,
                       &Bs[buf][row0 * 32]);
            }
        }
    };

    f32x4 acc[4][NF];
    #pragma unroll
    for (int i = 0; i < 4; ++i)
        #pragma unroll
        for (int j = 0; j < NF; ++j) { acc[i][j].x = 0.f; acc[i][j].y = 0.f; acc[i][j].z = 0.f; acc[i][j].w = 0.f; }

    stage(0, 0);
    __syncthreads();
    int cur = 0;

    for (int k0 = 0; k0 < K; k0 += 32) {
        if (k0 + 32 < K) stage(cur ^ 1, k0 + 32);

        f16x8 af[4], bfr[NF];
        #pragma unroll
        for (int mi = 0; mi < 4; ++mi)
            af[mi] = *(const f16x8*)&As[cur][(wr * 64 + mi * 16 + (lane & 15)) * 32 + (lane >> 4) * 8];
        #pragma unroll
        for (int ni = 0; ni < NF; ++ni)
            bfr[ni] = *(const f16x8*)&Bs[cur][(wc * (BN / 2) + ni * 16 + (lane & 15)) * BSTR + (lane >> 4) * 8];
        #pragma unroll
        for (int mi = 0; mi < 4; ++mi)
            #pragma unroll
            for (int ni = 0; ni < NF; ++ni)
                acc[mi][ni] = __builtin_amdgcn_mfma_f32_16x16x32_f16(af[mi], bfr[ni], acc[mi][ni], 0, 0, 0);
        __syncthreads();
        cur ^= 1;
    }

    #pragma unroll
    for (int mi = 0; mi < 4; ++mi) {
        #pragma unroll
        for (int ni = 0; ni < NF; ++ni) {
            #pragma unroll
            for (int j = 0; j < 4; ++j) {
                const int row = wr * 64 + mi * 16 + (lane >> 4) * 4 + j;
                const int col = n0 + wc * (BN / 2) + ni * 16 + (lane & 15);
                float v = acc[mi][ni][j] * alpha;
                if (CMODE == 2) { v += bias[col]; v = fmaxf(v, 0.f); }
                if (CMODE == 2) ((float*)Cp)[coff + (long)row * ldc + col] = v;
                else ((unsigned short*)Cp)[coff + (long)row * ldc + col] = cvth1(v);
            }
        }
    }
}

// ---------------------------------------------------------------------------
// split-K reduce (fp16 partials): out = relu(sum_ks p[ks] + bias), 8/thread.
// ---------------------------------------------------------------------------
__global__ __launch_bounds__(256)
void splitk_reduce(const unsigned short* __restrict__ part,
                   const float* __restrict__ bias, float* __restrict__ out)
{
    const long idx = ((long)blockIdx.x * 256 + threadIdx.x) * 8;
    const int o = (int)(idx & 1023);
    const f16x8 p0 = *(const f16x8*)(part + idx);
    const f16x8 p1 = *(const f16x8*)(part + 2097152 + idx);
    const f16x8 p2 = *(const f16x8*)(part + 2 * 2097152 + idx);
    const f16x8 p3 = *(const f16x8*)(part + 3 * 2097152 + idx);
    const float4 b0 = *(const float4*)(bias + o);
    const float4 b1 = *(const float4*)(bias + o + 4);
    float r[8];
    #pragma unroll
    for (int j = 0; j < 8; ++j) {
        const float bv = j < 4 ? (&b0.x)[j] : (&b1.x)[j - 4];
        r[j] = fmaxf((float)p0[j] + (float)p1[j] + (float)p2[j] + (float)p3[j] + bv, 0.f);
    }
    *(float4*)(out + idx)     = *(float4*)&r[0];
    *(float4*)(out + idx + 4) = *(float4*)&r[4];
}

// ---------------------------------------------------------------------------
__global__ __launch_bounds__(256)
void cvt_f16(const float* __restrict__ in, unsigned short* __restrict__ out)
{
    const long i8 = ((long)blockIdx.x * 256 + threadIdx.x) * 8;
    const float4 f0 = *(const float4*)(in + i8), f1 = *(const float4*)(in + i8 + 4);
    uint4 p;
    p.x = cvth2(f0.x, f0.y); p.y = cvth2(f0.z, f0.w);
    p.z = cvth2(f1.x, f1.y); p.w = cvth2(f1.z, f1.w);
    *(uint4*)(out + i8) = p;
}

// ---------------------------------------------------------------------------
// GEMM1 fused + xT PRODUCER (R22 version, best measured): A = otwH fp16
// glds dbuf, B = x fp32 reg-staged dbuf (head-major remap). The staged fp16
// B-tile IS the xT data, so each block also writes the transposed tile
// xT[nn][d][i] for its 8 k-steps where k0>>8 == mm.
// ---------------------------------------------------------------------------
__global__ __launch_bounds__(256)
void gemm1_exp(const unsigned short* __restrict__ otwH, const float* __restrict__ x,
               unsigned short* __restrict__ ekb, float* __restrict__ MiB,
               unsigned short* __restrict__ xTo)
{
    const int zb = blockIdx.x;
    const int nn = zb & 15, mm = zb >> 4;
    const int bt = nn * 4 + mm;               // canonical tile index
    const unsigned short* A = otwH + (long)mm * (OUT_SIZE * IN_DIM);
    const float* B = x + (long)nn * (IN_SIZE * IN_DIM);
    const int n0 = blockIdx.z * 128;          // i-chunk

    __shared__ short As[2][128 * 32];
    __shared__ short Bs[2][128 * 40];
    __shared__ float colmax[2][128];

    const int t = threadIdx.x;
    const int lane = t & 63;
    const int w = t >> 6, wr = w >> 1, wc = w & 1;
    const int lrow = lane >> 2, lce = (lane & 3) * 8;

    auto stage = [&](int buf, int k0) {
        #pragma unroll
        for (int j = 0; j < 2; ++j) {
            const int row0 = (w * 2 + j) * 16;
            glds16(A + (long)(row0 + lrow) * 1024 + k0 + lce, &As[buf][row0 * 32]);
        }
        #pragma unroll
        for (int itr = 0; itr < 2; ++itr) {
            const int idx = itr * 256 + t;
            const int row = idx >> 2, kq = idx & 3;
            const float* s = B + (long)(n0 + row) * 1024 + k0 + kq * 8;
            const float4 f0 = *(const float4*)s, f1 = *(const float4*)(s + 4);
            uint4 p;
            p.x = cvth2(f0.x, f0.y); p.y = cvth2(f0.z, f0.w);
            p.z = cvth2(f1.x, f1.y); p.w = cvth2(f1.z, f1.w);
            *(uint4*)&Bs[buf][row * 40 + kq * 8] = p;
        }
    };

    f32x4 acc[4][4];
    #pragma unroll
    for (int i = 0; i < 4; ++i)
        #pragma unroll
        for (int j = 0; j < 4; ++j) { acc[i][j].x = 0.f; acc[i][j].y = 0.f; acc[i][j].z = 0.f; acc[i][j].w = 0.f; }

    stage(0, 0);
    __syncthreads();
    int cur = 0;

    unsigned short* xTn = xTo + (long)nn * (IN_SIZE * IN_DIM);

    for (int k0 = 0; k0 < 1024; k0 += 32) {
        if (k0 + 32 < 1024) stage(cur ^ 1, k0 + 32);

        f16x8 af[4], bfr[4];
        #pragma unroll
        for (int mi = 0; mi < 4; ++mi)
            af[mi] = *(const f16x8*)&As[cur][(wr * 64 + mi * 16 + (lane & 15)) * 32 + (lane >> 4) * 8];
        #pragma unroll
        for (int ni = 0; ni < 4; ++ni)
            bfr[ni] = *(const f16x8*)&Bs[cur][(wc * 64 + ni * 16 + (lane & 15)) * 40 + (lane >> 4) * 8];
        #pragma unroll
        for (int mi = 0; mi < 4; ++mi)
            #pragma unroll
            for (int ni = 0; ni < 4; ++ni)
                acc[mi][ni] = __builtin_amdgcn_mfma_f32_16x16x32_f16(af[mi], bfr[ni], acc[mi][ni], 0, 0, 0);

        // ---- transposed xT write for this block's d-range (1/4 of steps) ----
        if ((k0 >> 8) == mm) {
            const int dl = t & 31;            // d within the 32-wide k-step
            const int ig = (t >> 5) * 16;     // i-group base (8 groups of 16)
            unsigned short tmp[16];
            #pragma unroll
            for (int j = 0; j < 16; ++j)
                tmp[j] = (unsigned short)Bs[cur][(ig + j) * 40 + dl];
            unsigned short* dst = xTn + (long)(k0 + dl) * IN_SIZE + n0 + ig;
            *(uint4*)dst       = *(uint4*)&tmp[0];
            *(uint4*)(dst + 8) = *(uint4*)&tmp[8];
        }
        __syncthreads();
        cur ^= 1;
    }

    float lm[4];
    #pragma unroll
    for (int ni = 0; ni < 4; ++ni) {
        float mx = -INFINITY;
        #pragma unroll
        for (int mi = 0; mi < 4; ++mi)
            #pragma unroll
            for (int j = 0; j < 4; ++j) mx = fmaxf(mx, acc[mi][ni][j]);
        mx *= 10.0f;
        mx = fmaxf(mx, __shfl_xor(mx, 16, 64));
        mx = fmaxf(mx, __shfl_xor(mx, 32, 64));
        lm[ni] = mx;
    }
    if ((lane >> 4) == 0) {
        #pragma unroll
        for (int ni = 0; ni < 4; ++ni) colmax[wr][wc * 64 + ni * 16 + lane] = lm[ni];
    }
    __syncthreads();
    float cm[4];
    #pragma unroll
    for (int ni = 0; ni < 4; ++ni) {
        const int c = wc * 64 + ni * 16 + (lane & 15);
        cm[ni] = fmaxf(colmax[0][c], colmax[1][c]);
    }
    if (wr == 0 && (lane >> 4) == 0) {
        #pragma unroll
        for (int ni = 0; ni < 4; ++ni)
            MiB[(long)bt * 1024 + n0 + wc * 64 + ni * 16 + lane] = cm[ni];
    }
    unsigned short* ekz = ekb + (long)bt * (OUT_SIZE * IN_SIZE);
    #pragma unroll
    for (int mi = 0; mi < 4; ++mi) {
        #pragma unroll
        for (int ni = 0; ni < 4; ++ni) {
            const int col = n0 + wc * 64 + ni * 16 + (lane & 15);
            #pragma unroll
            for (int j = 0; j < 4; ++j) {
                const int row = wr * 64 + mi * 16 + (lane >> 4) * 4 + j;
                ekz[(long)row * 1024 + col] = bf16rne(__expf(fmaf(acc[mi][ni][j], 10.f, -cm[ni])));
            }
        }
    }
}

// ---------------------------------------------------------------------------
// Sinkhorn v7 (fastest measured): 4-way split, 1024 threads, co-located
// siblings on XCD b%8 (grid 64x1x4), 8 barriers/iter, relaxed spin,
// writes T fp16 over the dead ek region. [R23 lesson: fusing this with
// gemm1 into one 1-block/CU kernel loses inter-block TLP and regresses.]
// ---------------------------------------------------------------------------
__global__ __launch_bounds__(1024)
void sinkhorn_split(unsigned short* __restrict__ ekb,
                    const float* __restrict__ MiB,
                    float* __restrict__ xchg, unsigned int* __restrict__ ctr)
{
    const int b = blockIdx.x;          // tile 0..63 (XCD-aligned)
    const int q = blockIdx.z;          // i-quarter 0..3
    const int t = threadIdx.x;
    const int lane = t & 63, w = t >> 6;

    __shared__ unsigned ekw[128 * 129];
    __shared__ float part_u[8][256];
    __shared__ float part_v[8][128];
    __shared__ float eu_l[256];
    __shared__ float v_s[128], ev_s[128];
    __shared__ float red8[8];
    __shared__ float wg_s;

    {
        const unsigned short* src = ekb + (long)b * 131072 + q * 256;
        #pragma unroll
        for (int j = 0; j < 4; ++j) {
            const int idx = t + 1024 * j;
            const int s = idx >> 5, c8 = (idx & 31) * 8;
            const uint4 p = *(const uint4*)(src + (long)s * 1024 + c8);
            const int bd = s * 129 + (c8 >> 1);
            ekw[bd] = p.x; ekw[bd + 1] = p.y; ekw[bd + 2] = p.z; ekw[bd + 3] = p.w;
        }
    }
    float mi_t = 0.f, u_reg = 0.f, w_t = 0.f;
    if (t < 256) mi_t = MiB[(long)b * 1024 + q * 256 + t];
    if (t < 128) { v_s[t] = 0.f; ev_s[t] = 1.0f; }
    __syncthreads();

    const float A0 = -2.0794415416798357f;
    float vmx = 0.f;

    for (int it = 0; it < MAX_ITER; ++it) {
        {
            const int p = t & 127, sq = t >> 7;
            float s0 = 0.f, s1 = 0.f;
            #pragma unroll
            for (int j = 0; j < 16; ++j) {
                const int s = sq * 16 + j;
                const unsigned e = ekw[s * 129 + p];
                const float evv = ev_s[s];
                s0 = fmaf(__uint_as_float(e << 16),          evv, s0);
                s1 = fmaf(__uint_as_float(e & 0xffff0000u),  evv, s1);
            }
            part_u[sq][2 * p]     = s0;
            part_u[sq][2 * p + 1] = s1;
        }
        __syncthreads();

        if (t < 256) {
            float S = part_u[0][t];
            #pragma unroll
            for (int g = 1; g < 8; ++g) S += part_u[g][t];
            const float un = A0 - u_reg - mi_t - vmx - __logf(S);
            u_reg = un;
            w_t = mi_t + un;
            float wl = w_t;
            #pragma unroll
            for (int m = 1; m < 64; m <<= 1) wl = fmaxf(wl, __shfl_xor(wl, m, 64));
            if (lane == 0) red8[4 + w] = wl;
        }
        __syncthreads();
        const float wmx_l = fmaxf(fmaxf(red8[4], red8[5]), fmaxf(red8[6], red8[7]));
        if (t < 256) eu_l[t] = __expf(w_t - wmx_l);
        __syncthreads();

        {
            const int s = t & 127, g = t >> 7;
            float acc = 0.f;
            #pragma unroll
            for (int j = 0; j < 16; ++j) {
                const int p = 16 * g + j;
                const unsigned e = ekw[s * 129 + p];
                const float2 eup = *(const float2*)&eu_l[2 * p];
                acc = fmaf(__uint_as_float(e << 16),         eup.x, acc);
                acc = fmaf(__uint_as_float(e & 0xffff0000u), eup.y, acc);
            }
            part_v[g][s] = acc;
        }
        __syncthreads();

        float* slot = xchg + ((long)(b * MAX_ITER + it) * 4 + q) * 160;
        if (t < 128) {
            float cp_l = part_v[0][t];
            #pragma unroll
            for (int g = 1; g < 8; ++g) cp_l += part_v[g][t];
            __hip_atomic_store(slot + t, cp_l, __ATOMIC_RELAXED, __HIP_MEMORY_SCOPE_AGENT);
        }
        if (t == 0)
            __hip_atomic_store(slot + 128, wmx_l, __ATOMIC_RELAXED, __HIP_MEMORY_SCOPE_AGENT);
        __syncthreads();
        if (t == 0) {
            unsigned int* c = ctr + b * MAX_ITER + it;
            __hip_atomic_fetch_add(c, 1u, __ATOMIC_RELEASE, __HIP_MEMORY_SCOPE_AGENT);
            while (__hip_atomic_load(c, __ATOMIC_RELAXED, __HIP_MEMORY_SCOPE_AGENT) < 4u) {}
            (void)__hip_atomic_load(c, __ATOMIC_ACQUIRE, __HIP_MEMORY_SCOPE_AGENT);
        }
        __syncthreads();

        if (t < 128) {
            float* base = xchg + (long)(b * MAX_ITER + it) * 4 * 160;
            const float w0 = __hip_atomic_load(base + 0 * 160 + 128, __ATOMIC_RELAXED, __HIP_MEMORY_SCOPE_AGENT);
            const float w1 = __hip_atomic_load(base + 1 * 160 + 128, __ATOMIC_RELAXED, __HIP_MEMORY_SCOPE_AGENT);
            const float w2 = __hip_atomic_load(base + 2 * 160 + 128, __ATOMIC_RELAXED, __HIP_MEMORY_SCOPE_AGENT);
            const float w3 = __hip_atomic_load(base + 3 * 160 + 128, __ATOMIC_RELAXED, __HIP_MEMORY_SCOPE_AGENT);
            const float wg = fmaxf(fmaxf(w0, w1), fmaxf(w2, w3));
            const float c0 = __hip_atomic_load(base + 0 * 160 + t, __ATOMIC_RELAXED, __HIP_MEMORY_SCOPE_AGENT);
            const float c1 = __hip_atomic_load(base + 1 * 160 + t, __ATOMIC_RELAXED, __HIP_MEMORY_SCOPE_AGENT);
            const float c2 = __hip_atomic_load(base + 2 * 160 + t, __ATOMIC_RELAXED, __HIP_MEMORY_SCOPE_AGENT);
            const float c3 = __hip_atomic_load(base + 3 * 160 + t, __ATOMIC_RELAXED, __HIP_MEMORY_SCOPE_AGENT);
            const float cp = c0 * __expf(w0 - wg) + c1 * __expf(w1 - wg)
                           + c2 * __expf(w2 - wg) + c3 * __expf(w3 - wg);
            const float vn = -v_s[t] - wg - __logf(cp);
            v_s[t] = vn;
            if (t == 0) wg_s = wg;
            float xv = vn;
            #pragma unroll
            for (int m = 1; m < 64; m <<= 1) xv = fmaxf(xv, __shfl_xor(xv, m, 64));
            if (lane == 0) red8[w] = xv;
        }
        __syncthreads();
        vmx = fmaxf(red8[0], red8[1]);
        if (t < 128) ev_s[t] = __expf(v_s[t] - vmx);
        __syncthreads();
    }

    const float wg = wg_s;
    if (t < 256) eu_l[t] = __expf(w_t - wg);
    if (t < 128) ev_s[t] = __expf(v_s[t] + wg);
    __syncthreads();
    unsigned short* To = ekb + (long)b * 131072 + q * 256;
    #pragma unroll
    for (int j = 0; j < 16; ++j) {
        const int idx = t + 1024 * j;
        const int s  = idx >> 7;
        const int ip = idx & 127;
        const unsigned e = ekw[s * 129 + ip];
        const float2 eup = *(const float2*)&eu_l[2 * ip];
        const float ec = ev_s[s];
        const float lo = __uint_as_float(e << 16)         * eup.x * ec;
        const float hi = __uint_as_float(e & 0xffff0000u) * eup.y * ec;
        *(unsigned*)(To + (long)s * 1024 + ip * 2) = cvth2(lo, hi);
    }
}

// ---------------------------------------------------------------------------
extern "C" void kernel_launch(void* const* d_in, const int* in_sizes, int n_in,
                              void* d_out, int out_size, void* d_ws, size_t ws_size,
                              hipStream_t stream)
{
    const float* x     = (const float*)d_in[0];   // [16][1024][1024]
    const float* otw   = (const float*)d_in[1];   // [4][128][1024]
    const float* lin_w = (const float*)d_in[2];   // [1024][4096]
    const float* lin_b = (const float*)d_in[3];   // [1024]
    float* out = (float*)d_out;                   // [16][128][1024] fp32 (8 MB)

    // ws (64 MB): [0,32M) xT fp16 (dead after GEMM2 -> fp16 split-K partials)
    //             [32M,48M) ek bf16 -> T fp16 in-place; [48M,64M) feat fp16
    unsigned short* xT   = (unsigned short*)d_ws;
    unsigned short* ekb  = xT + 16777216;
    unsigned short* feat = ekb + 8388608;
    unsigned short* partial = (unsigned short*)d_ws;  // [4][16][128][1024] fp16
    // d_out scratch (fully overwritten by splitk_reduce):
    //   Mi [64][1024] f32 @0 ; xchg [64][10][4][160] f32 @131072 ;
    //   ctr [64][10] u32 @655360 ; otwH fp16 @786432
    float* MiB  = (float*)d_out;
    float* xchg = MiB + 131072;
    unsigned int* ctrB = (unsigned int*)(MiB + 655360);
    unsigned short* otwH = (unsigned short*)(MiB + 786432);

    hipMemsetAsync(ctrB, 0, 64 * MAX_ITER * sizeof(unsigned int), stream);

    // -1) otw -> fp16 (tiny)
    cvt_f16<<<dim3(256), 256, 0, stream>>>(otw, otwH);

    // 1) fused K-GEMM + colmax + exp + xT producer (transpose_cvt fused in)
    gemm1_exp<<<dim3(64, 1, 8), 256, 0, stream>>>(otwH, x, ekb, MiB, xT);

    // 2) Sinkhorn v7 -> T fp16 over ek
    sinkhorn_split<<<dim3(64, 1, 4), 1024, 0, stream>>>(ekb, MiB, xchg, ctrB);

    // 3) feat = T . xT^T: NF=2, grid (64,1,16) = 4 blocks/CU, HMAP
    mfma_gemm<false, 1, 2, true, true><<<dim3(64, 1, 16), 256, 0, stream>>>(
        ekb, xT, nullptr, feat,
        1024, 1024, 1024, 1024, 4,
        0, 131072, 1048576, 0, 0, 131072, 1.0f);

    // 4) split-K x4 GEMM3 -> fp16 partials (CMODE 1)
    mfma_gemm<true, 1, 2, false, false><<<dim3(16, 1, 64), 256, 0, stream>>>(
        feat, lin_w, nullptr, partial,
        1024, 1024, 4096, 1024, 16,
        131072, 524288, 1024, 0, 2097152, 131072, 1.0f);

    // 5) out = relu(sum_ks partial + bias)
    splitk_reduce<<<dim3(1024), 256, 0, stream>>>(partial, lin_b, out);
}

// Round 26
// 174.755 us; speedup vs baseline: 1.0239x; 1.0013x over previous
//
#include <hip/hip_runtime.h>
#include <math.h>

#define EPSV 0.1f
#define MAX_ITER 10
constexpr int NB       = 16;
constexpr int IN_SIZE  = 1024;
constexpr int IN_DIM   = 1024;
constexpr int HEADS    = 4;
constexpr int OUT_SIZE = 128;
constexpr int OUT_DIM  = 1024;

typedef __attribute__((ext_vector_type(8))) _Float16 f16x8;
typedef __attribute__((ext_vector_type(4))) float f32x4;

__device__ __forceinline__ unsigned cvth2(float lo, float hi) {
    _Float16 a = (_Float16)lo, b = (_Float16)hi;
    unsigned short ua = *(unsigned short*)&a, ub = *(unsigned short*)&b;
    return (unsigned)ua | ((unsigned)ub << 16);
}
__device__ __forceinline__ unsigned short cvth1(float f) {
    _Float16 a = (_Float16)f;
    return *(unsigned short*)&a;
}
__device__ __forceinline__ unsigned short bf16rne(float f) {
    unsigned a = __float_as_uint(f);
    return (unsigned short)((a + 0x7fffu + ((a >> 16) & 1u)) >> 16);
}
// async global->LDS, 16 B per lane: HW writes lane l at ldsbase + l*16.
__device__ __forceinline__ void glds16(const void* g, void* l) {
    __builtin_amdgcn_global_load_lds(
        (const __attribute__((address_space(1))) unsigned int*)g,
        (__attribute__((address_space(3))) unsigned int*)l, 16, 0, 0);
}

// ---------------------------------------------------------------------------
// MFMA fp16 GEMM, M fixed 128, double-buffered. A fp16 glds (linear LDS
// [rows][32]); B fp16 glds or fp32 reg-staged (padded 40).
// CMODE: 1 = fp16 store, 2 = f32+bias+relu
// HMAP : head-major tile remap (z&15=n, z>>4=m, b=n*4+m) -> all 4 heads of
//        batch n on XCD n%8: shared B slab fetched once per XCD.
// ---------------------------------------------------------------------------
template<bool B_F32, int CMODE, int NF, bool SWAP, bool HMAP>
__global__ __launch_bounds__(256)
void mfma_gemm(const void* __restrict__ Ap, const void* __restrict__ Bp,
               const float* __restrict__ bias, void* __restrict__ Cp,
               int K, int lda, int ldb, int ldc, int div,
               long AsN, long AsM, long BsN, long BsM, long CsN, long CsM,
               float alpha)
{
    constexpr int BN   = NF * 32;
    constexpr int BSTR = B_F32 ? 40 : 32;   // B LDS row stride (elems)
    const int z  = SWAP ? blockIdx.x : blockIdx.z;
    const int n0 = (SWAP ? blockIdx.z : blockIdx.x) * BN;
    long aoff, boff, coff;
    if (HMAP) {
        const int nn = z & 15, mm = z >> 4, bt = nn * 4 + mm;
        aoff = (long)bt * AsM; boff = (long)nn * BsN; coff = (long)bt * CsM;
    } else {
        aoff = (long)(z / div) * AsN + (long)(z % div) * AsM;
        boff = (long)(z / div) * BsN + (long)(z % div) * BsM;
        coff = (long)(z / div) * CsN + (long)(z % div) * CsM;
    }

    __shared__ short As[2][128 * 32];
    __shared__ short Bs[2][BN * BSTR];

    const int t = threadIdx.x;
    const int lane = t & 63;
    const int w = t >> 6, wr = w >> 1, wc = w & 1;
    const int lrow = lane >> 2, lce = (lane & 3) * 8;   // glds lane mapping

    auto stage = [&](int buf, int k0) {
        const long abase = aoff + k0;
        const long bbase = boff + k0;
        #pragma unroll
        for (int j = 0; j < 2; ++j) {
            const int row0 = (w * 2 + j) * 16;
            glds16((const short*)Ap + abase + (long)(row0 + lrow) * lda + lce,
                   &As[buf][row0 * 32]);
        }
        if (B_F32) {
            #pragma unroll
            for (int itr = 0; itr < BN / 64; ++itr) {
                const int idx = itr * 256 + t;
                const int row = idx >> 2, kq = idx & 3;
                const float* s = (const float*)Bp + bbase + (long)(n0 + row) * ldb + kq * 8;
                const float4 f0 = *(const float4*)s, f1 = *(const float4*)(s + 4);
                uint4 p;
                p.x = cvth2(f0.x, f0.y); p.y = cvth2(f0.z, f0.w);
                p.z = cvth2(f1.x, f1.y); p.w = cvth2(f1.z, f1.w);
                *(uint4*)&Bs[buf][row * BSTR + kq * 8] = p;
            }
        } else {
            #pragma unroll
            for (int j = 0; j < BN / 64; ++j) {
                const int row0 = (w * (BN / 64) + j) * 16;
                glds16((const short*)Bp + bbase + (long)(n0 + row0 + lrow) * ldb + lce,
                       &Bs[buf][row0 * 32]);
            }
        }
    };

    f32x4 acc[4][NF];
    #pragma unroll
    for (int i = 0; i < 4; ++i)
        #pragma unroll
        for (int j = 0; j < NF; ++j) { acc[i][j].x = 0.f; acc[i][j].y = 0.f; acc[i][j].z = 0.f; acc[i][j].w = 0.f; }

    stage(0, 0);
    __syncthreads();
    int cur = 0;

    for (int k0 = 0; k0 < K; k0 += 32) {
        if (k0 + 32 < K) stage(cur ^ 1, k0 + 32);

        f16x8 af[4], bfr[NF];
        #pragma unroll
        for (int mi = 0; mi < 4; ++mi)
            af[mi] = *(const f16x8*)&As[cur][(wr * 64 + mi * 16 + (lane & 15)) * 32 + (lane >> 4) * 8];
        #pragma unroll
        for (int ni = 0; ni < NF; ++ni)
            bfr[ni] = *(const f16x8*)&Bs[cur][(wc * (BN / 2) + ni * 16 + (lane & 15)) * BSTR + (lane >> 4) * 8];
        #pragma unroll
        for (int mi = 0; mi < 4; ++mi)
            #pragma unroll
            for (int ni = 0; ni < NF; ++ni)
                acc[mi][ni] = __builtin_amdgcn_mfma_f32_16x16x32_f16(af[mi], bfr[ni], acc[mi][ni], 0, 0, 0);
        __syncthreads();
        cur ^= 1;
    }

    #pragma unroll
    for (int mi = 0; mi < 4; ++mi) {
        #pragma unroll
        for (int ni = 0; ni < NF; ++ni) {
            #pragma unroll
            for (int j = 0; j < 4; ++j) {
                const int row = wr * 64 + mi * 16 + (lane >> 4) * 4 + j;
                const int col = n0 + wc * (BN / 2) + ni * 16 + (lane & 15);
                float v = acc[mi][ni][j] * alpha;
                if (CMODE == 2) { v += bias[col]; v = fmaxf(v, 0.f); }
                if (CMODE == 2) ((float*)Cp)[coff + (long)row * ldc + col] = v;
                else ((unsigned short*)Cp)[coff + (long)row * ldc + col] = cvth1(v);
            }
        }
    }
}

// ---------------------------------------------------------------------------
// split-K reduce (fp16 partials): out = relu(sum_ks p[ks] + bias), 8/thread.
// ---------------------------------------------------------------------------
__global__ __launch_bounds__(256)
void splitk_reduce(const unsigned short* __restrict__ part,
                   const float* __restrict__ bias, float* __restrict__ out)
{
    const long idx = ((long)blockIdx.x * 256 + threadIdx.x) * 8;
    const int o = (int)(idx & 1023);
    const f16x8 p0 = *(const f16x8*)(part + idx);
    const f16x8 p1 = *(const f16x8*)(part + 2097152 + idx);
    const f16x8 p2 = *(const f16x8*)(part + 2 * 2097152 + idx);
    const f16x8 p3 = *(const f16x8*)(part + 3 * 2097152 + idx);
    const float4 b0 = *(const float4*)(bias + o);
    const float4 b1 = *(const float4*)(bias + o + 4);
    float r[8];
    #pragma unroll
    for (int j = 0; j < 8; ++j) {
        const float bv = j < 4 ? (&b0.x)[j] : (&b1.x)[j - 4];
        r[j] = fmaxf((float)p0[j] + (float)p1[j] + (float)p2[j] + (float)p3[j] + bv, 0.f);
    }
    *(float4*)(out + idx)     = *(float4*)&r[0];
    *(float4*)(out + idx + 4) = *(float4*)&r[4];
}

// ---------------------------------------------------------------------------
__global__ __launch_bounds__(256)
void cvt_f16(const float* __restrict__ in, unsigned short* __restrict__ out)
{
    const long i8 = ((long)blockIdx.x * 256 + threadIdx.x) * 8;
    const float4 f0 = *(const float4*)(in + i8), f1 = *(const float4*)(in + i8 + 4);
    uint4 p;
    p.x = cvth2(f0.x, f0.y); p.y = cvth2(f0.z, f0.w);
    p.z = cvth2(f1.x, f1.y); p.w = cvth2(f1.z, f1.w);
    *(uint4*)(out + i8) = p;
}

// ---------------------------------------------------------------------------
// GEMM1 fused + xT PRODUCER (R22 version): A = otwH fp16 glds dbuf,
// B = x fp32 reg-staged dbuf (head-major remap). Also writes xT[nn][d][i]
// for its 8 k-steps where k0>>8 == mm.
// ---------------------------------------------------------------------------
__global__ __launch_bounds__(256)
void gemm1_exp(const unsigned short* __restrict__ otwH, const float* __restrict__ x,
               unsigned short* __restrict__ ekb, float* __restrict__ MiB,
               unsigned short* __restrict__ xTo)
{
    const int zb = blockIdx.x;
    const int nn = zb & 15, mm = zb >> 4;
    const int bt = nn * 4 + mm;               // canonical tile index
    const unsigned short* A = otwH + (long)mm * (OUT_SIZE * IN_DIM);
    const float* B = x + (long)nn * (IN_SIZE * IN_DIM);
    const int n0 = blockIdx.z * 128;          // i-chunk

    __shared__ short As[2][128 * 32];
    __shared__ short Bs[2][128 * 40];
    __shared__ float colmax[2][128];

    const int t = threadIdx.x;
    const int lane = t & 63;
    const int w = t >> 6, wr = w >> 1, wc = w & 1;
    const int lrow = lane >> 2, lce = (lane & 3) * 8;

    auto stage = [&](int buf, int k0) {
        #pragma unroll
        for (int j = 0; j < 2; ++j) {
            const int row0 = (w * 2 + j) * 16;
            glds16(A + (long)(row0 + lrow) * 1024 + k0 + lce, &As[buf][row0 * 32]);
        }
        #pragma unroll
        for (int itr = 0; itr < 2; ++itr) {
            const int idx = itr * 256 + t;
            const int row = idx >> 2, kq = idx & 3;
            const float* s = B + (long)(n0 + row) * 1024 + k0 + kq * 8;
            const float4 f0 = *(const float4*)s, f1 = *(const float4*)(s + 4);
            uint4 p;
            p.x = cvth2(f0.x, f0.y); p.y = cvth2(f0.z, f0.w);
            p.z = cvth2(f1.x, f1.y); p.w = cvth2(f1.z, f1.w);
            *(uint4*)&Bs[buf][row * 40 + kq * 8] = p;
        }
    };

    f32x4 acc[4][4];
    #pragma unroll
    for (int i = 0; i < 4; ++i)
        #pragma unroll
        for (int j = 0; j < 4; ++j) { acc[i][j].x = 0.f; acc[i][j].y = 0.f; acc[i][j].z = 0.f; acc[i][j].w = 0.f; }

    stage(0, 0);
    __syncthreads();
    int cur = 0;

    unsigned short* xTn = xTo + (long)nn * (IN_SIZE * IN_DIM);

    for (int k0 = 0; k0 < 1024; k0 += 32) {
        if (k0 + 32 < 1024) stage(cur ^ 1, k0 + 32);

        f16x8 af[4], bfr[4];
        #pragma unroll
        for (int mi = 0; mi < 4; ++mi)
            af[mi] = *(const f16x8*)&As[cur][(wr * 64 + mi * 16 + (lane & 15)) * 32 + (lane >> 4) * 8];
        #pragma unroll
        for (int ni = 0; ni < 4; ++ni)
            bfr[ni] = *(const f16x8*)&Bs[cur][(wc * 64 + ni * 16 + (lane & 15)) * 40 + (lane >> 4) * 8];
        #pragma unroll
        for (int mi = 0; mi < 4; ++mi)
            #pragma unroll
            for (int ni = 0; ni < 4; ++ni)
                acc[mi][ni] = __builtin_amdgcn_mfma_f32_16x16x32_f16(af[mi], bfr[ni], acc[mi][ni], 0, 0, 0);

        // ---- transposed xT write for this block's d-range (1/4 of steps) ----
        if ((k0 >> 8) == mm) {
            const int dl = t & 31;            // d within the 32-wide k-step
            const int ig = (t >> 5) * 16;     // i-group base (8 groups of 16)
            unsigned short tmp[16];
            #pragma unroll
            for (int j = 0; j < 16; ++j)
                tmp[j] = (unsigned short)Bs[cur][(ig + j) * 40 + dl];
            unsigned short* dst = xTn + (long)(k0 + dl) * IN_SIZE + n0 + ig;
            *(uint4*)dst       = *(uint4*)&tmp[0];
            *(uint4*)(dst + 8) = *(uint4*)&tmp[8];
        }
        __syncthreads();
        cur ^= 1;
    }

    float lm[4];
    #pragma unroll
    for (int ni = 0; ni < 4; ++ni) {
        float mx = -INFINITY;
        #pragma unroll
        for (int mi = 0; mi < 4; ++mi)
            #pragma unroll
            for (int j = 0; j < 4; ++j) mx = fmaxf(mx, acc[mi][ni][j]);
        mx *= 10.0f;
        mx = fmaxf(mx, __shfl_xor(mx, 16, 64));
        mx = fmaxf(mx, __shfl_xor(mx, 32, 64));
        lm[ni] = mx;
    }
    if ((lane >> 4) == 0) {
        #pragma unroll
        for (int ni = 0; ni < 4; ++ni) colmax[wr][wc * 64 + ni * 16 + lane] = lm[ni];
    }
    __syncthreads();
    float cm[4];
    #pragma unroll
    for (int ni = 0; ni < 4; ++ni) {
        const int c = wc * 64 + ni * 16 + (lane & 15);
        cm[ni] = fmaxf(colmax[0][c], colmax[1][c]);
    }
    if (wr == 0 && (lane >> 4) == 0) {
        #pragma unroll
        for (int ni = 0; ni < 4; ++ni)
            MiB[(long)bt * 1024 + n0 + wc * 64 + ni * 16 + lane] = cm[ni];
    }
    unsigned short* ekz = ekb + (long)bt * (OUT_SIZE * IN_SIZE);
    #pragma unroll
    for (int mi = 0; mi < 4; ++mi) {
        #pragma unroll
        for (int ni = 0; ni < 4; ++ni) {
            const int col = n0 + wc * 64 + ni * 16 + (lane & 15);
            #pragma unroll
            for (int j = 0; j < 4; ++j) {
                const int row = wr * 64 + mi * 16 + (lane >> 4) * 4 + j;
                ekz[(long)row * 1024 + col] = bf16rne(__expf(fmaf(acc[mi][ni][j], 10.f, -cm[ni])));
            }
        }
    }
}

// ---------------------------------------------------------------------------
// Sinkhorn v8: LAGGED NORMALIZERS -> 6 barriers/iter (was 8). The eu/ev
// exp-normalizers use the PREVIOUS iteration's block max (double-buffered
// LDS scalars T_s/S_s, updated by t0 inside existing phases). Exact: the
// normalizer is carried as the exchange tag and cancels in the combine
// (cp = sum_g cp_g * exp(tag_g - wg)) -- same machinery as v7, different
// tag value. exp args bounded by per-iteration drift (iter0: w in [-7,-2],
// tag 0). 4-way split, 1024 thr, siblings on XCD b%8 (grid 64x1x4).
// ---------------------------------------------------------------------------
__global__ __launch_bounds__(1024)
void sinkhorn_split(unsigned short* __restrict__ ekb,
                    const float* __restrict__ MiB,
                    float* __restrict__ xchg, unsigned int* __restrict__ ctr)
{
    const int b = blockIdx.x;          // tile 0..63 (XCD-aligned)
    const int q = blockIdx.z;          // i-quarter 0..3
    const int t = threadIdx.x;
    const int lane = t & 63, w = t >> 6;

    __shared__ unsigned ekw[128 * 129];
    __shared__ float part_u[8][256];
    __shared__ float part_v[8][128];
    __shared__ float eu_l[256];
    __shared__ float v_s[128], ev_s[128];
    __shared__ float red8[8];
    __shared__ float S_s[2], T_s[2];   // lagged vmax / wmax (double-buffered)
    __shared__ float wg_s;

    {
        const unsigned short* src = ekb + (long)b * 131072 + q * 256;
        #pragma unroll
        for (int j = 0; j < 4; ++j) {
            const int idx = t + 1024 * j;
            const int s = idx >> 5, c8 = (idx & 31) * 8;
            const uint4 p = *(const uint4*)(src + (long)s * 1024 + c8);
            const int bd = s * 129 + (c8 >> 1);
            ekw[bd] = p.x; ekw[bd + 1] = p.y; ekw[bd + 2] = p.z; ekw[bd + 3] = p.w;
        }
    }
    float mi_t = 0.f, u_reg = 0.f, w_t = 0.f;
    if (t < 256) mi_t = MiB[(long)b * 1024 + q * 256 + t];
    if (t < 128) { v_s[t] = 0.f; ev_s[t] = 1.0f; }
    if (t < 8) red8[t] = 0.f;
    if (t < 2) { S_s[t] = 0.f; T_s[t] = 0.f; }
    __syncthreads();

    const float A0 = -2.0794415416798357f;

    for (int it = 0; it < MAX_ITER; ++it) {
        // ---- phase 1: u-pass (+ t0 reduces prev vn-max partials) ----
        {
            const int p = t & 127, sq = t >> 7;
            float s0 = 0.f, s1 = 0.f;
            #pragma unroll
            for (int j = 0; j < 16; ++j) {
                const int s = sq * 16 + j;
                const unsigned e = ekw[s * 129 + p];
                const float evv = ev_s[s];
                s0 = fmaf(__uint_as_float(e << 16),          evv, s0);
                s1 = fmaf(__uint_as_float(e & 0xffff0000u),  evv, s1);
            }
            part_u[sq][2 * p]     = s0;
            part_u[sq][2 * p + 1] = s1;
        }
        if (t == 0) S_s[it & 1] = fmaxf(red8[0], red8[1]);   // M_{it-1}
        __syncthreads();                                     // B1

        // ---- phase 2: u update + eu (lagged normalizer) ----
        if (t < 256) {
            const float vmx = S_s[(it + 1) & 1];   // normalizer used in ev it consumes
            const float P   = T_s[it & 1];         // lagged w-normalizer
            float S = part_u[0][t];
            #pragma unroll
            for (int g = 1; g < 8; ++g) S += part_u[g][t];
            const float un = A0 - u_reg - mi_t - vmx - __logf(S);
            u_reg = un;
            w_t = mi_t + un;
            eu_l[t] = __expf(w_t - P);
            float wl = w_t;
            #pragma unroll
            for (int m = 1; m < 64; m <<= 1) wl = fmaxf(wl, __shfl_xor(wl, m, 64));
            if (lane == 0) red8[4 + w] = wl;
        }
        __syncthreads();                                     // B2

        // ---- phase 3: v-pass ----
        {
            const int s = t & 127, g = t >> 7;
            float acc = 0.f;
            #pragma unroll
            for (int j = 0; j < 16; ++j) {
                const int p = 16 * g + j;
                const unsigned e = ekw[s * 129 + p];
                const float2 eup = *(const float2*)&eu_l[2 * p];
                acc = fmaf(__uint_as_float(e << 16),         eup.x, acc);
                acc = fmaf(__uint_as_float(e & 0xffff0000u), eup.y, acc);
            }
            part_v[g][s] = acc;
        }
        __syncthreads();                                     // B3

        // ---- phase 4: publish (tag = lagged normalizer actually used) ----
        float* slot = xchg + ((long)(b * MAX_ITER + it) * 4 + q) * 160;
        if (t < 128) {
            float cp_l = part_v[0][t];
            #pragma unroll
            for (int g = 1; g < 8; ++g) cp_l += part_v[g][t];
            __hip_atomic_store(slot + t, cp_l, __ATOMIC_RELAXED, __HIP_MEMORY_SCOPE_AGENT);
        }
        if (t == 0) {
            __hip_atomic_store(slot + 128, T_s[it & 1], __ATOMIC_RELAXED, __HIP_MEMORY_SCOPE_AGENT);
            T_s[(it + 1) & 1] = fmaxf(fmaxf(red8[4], red8[5]), fmaxf(red8[6], red8[7]));
        }
        __syncthreads();                                     // B4 (drain)
        if (t == 0) {
            unsigned int* c = ctr + b * MAX_ITER + it;
            __hip_atomic_fetch_add(c, 1u, __ATOMIC_RELEASE, __HIP_MEMORY_SCOPE_AGENT);
            while (__hip_atomic_load(c, __ATOMIC_RELAXED, __HIP_MEMORY_SCOPE_AGENT) < 4u) {}
            (void)__hip_atomic_load(c, __ATOMIC_ACQUIRE, __HIP_MEMORY_SCOPE_AGENT);
        }
        __syncthreads();                                     // B5

        // ---- phase 5: combine + ev (lagged) + vn-max butterfly ----
        if (t < 128) {
            float* base = xchg + (long)(b * MAX_ITER + it) * 4 * 160;
            const float w0 = __hip_atomic_load(base + 0 * 160 + 128, __ATOMIC_RELAXED, __HIP_MEMORY_SCOPE_AGENT);
            const float w1 = __hip_atomic_load(base + 1 * 160 + 128, __ATOMIC_RELAXED, __HIP_MEMORY_SCOPE_AGENT);
            const float w2 = __hip_atomic_load(base + 2 * 160 + 128, __ATOMIC_RELAXED, __HIP_MEMORY_SCOPE_AGENT);
            const float w3 = __hip_atomic_load(base + 3 * 160 + 128, __ATOMIC_RELAXED, __HIP_MEMORY_SCOPE_AGENT);
            const float wg = fmaxf(fmaxf(w0, w1), fmaxf(w2, w3));
            const float c0 = __hip_atomic_load(base + 0 * 160 + t, __ATOMIC_RELAXED, __HIP_MEMORY_SCOPE_AGENT);
            const float c1 = __hip_atomic_load(base + 1 * 160 + t, __ATOMIC_RELAXED, __HIP_MEMORY_SCOPE_AGENT);
            const float c2 = __hip_atomic_load(base + 2 * 160 + t, __ATOMIC_RELAXED, __HIP_MEMORY_SCOPE_AGENT);
            const float c3 = __hip_atomic_load(base + 3 * 160 + t, __ATOMIC_RELAXED, __HIP_MEMORY_SCOPE_AGENT);
            const float cp = c0 * __expf(w0 - wg) + c1 * __expf(w1 - wg)
                           + c2 * __expf(w2 - wg) + c3 * __expf(w3 - wg);
            const float vn = -v_s[t] - wg - __logf(cp);
            v_s[t] = vn;
            ev_s[t] = __expf(vn - S_s[it & 1]);   // lagged normalizer
            if (t == 0) wg_s = wg;
            float xv = vn;
            #pragma unroll
            for (int m = 1; m < 64; m <<= 1) xv = fmaxf(xv, __shfl_xor(xv, m, 64));
            if (lane == 0) red8[w] = xv;          // waves 0..1
        }
        __syncthreads();                                     // B6
    }

    const float wg = wg_s;
    if (t < 256) eu_l[t] = __expf(w_t - wg);
    if (t < 128) ev_s[t] = __expf(v_s[t] + wg);
    __syncthreads();
    unsigned short* To = ekb + (long)b * 131072 + q * 256;
    #pragma unroll
    for (int j = 0; j < 16; ++j) {
        const int idx = t + 1024 * j;
        const int s  = idx >> 7;
        const int ip = idx & 127;
        const unsigned e = ekw[s * 129 + ip];
        const float2 eup = *(const float2*)&eu_l[2 * ip];
        const float ec = ev_s[s];
        const float lo = __uint_as_float(e << 16)         * eup.x * ec;
        const float hi = __uint_as_float(e & 0xffff0000u) * eup.y * ec;
        *(unsigned*)(To + (long)s * 1024 + ip * 2) = cvth2(lo, hi);
    }
}

// ---------------------------------------------------------------------------
extern "C" void kernel_launch(void* const* d_in, const int* in_sizes, int n_in,
                              void* d_out, int out_size, void* d_ws, size_t ws_size,
                              hipStream_t stream)
{
    const float* x     = (const float*)d_in[0];   // [16][1024][1024]
    const float* otw   = (const float*)d_in[1];   // [4][128][1024]
    const float* lin_w = (const float*)d_in[2];   // [1024][4096]
    const float* lin_b = (const float*)d_in[3];   // [1024]
    float* out = (float*)d_out;                   // [16][128][1024] fp32 (8 MB)

    // ws (64 MB): [0,32M) xT fp16 (dead after GEMM2 -> fp16 split-K partials)
    //             [32M,48M) ek bf16 -> T fp16 in-place; [48M,64M) feat fp16
    unsigned short* xT   = (unsigned short*)d_ws;
    unsigned short* ekb  = xT + 16777216;
    unsigned short* feat = ekb + 8388608;
    unsigned short* partial = (unsigned short*)d_ws;  // [4][16][128][1024] fp16
    // d_out scratch (fully overwritten by splitk_reduce):
    //   Mi [64][1024] f32 @0 ; xchg [64][10][4][160] f32 @131072 ;
    //   ctr [64][10] u32 @655360 ; otwH fp16 @786432
    float* MiB  = (float*)d_out;
    float* xchg = MiB + 131072;
    unsigned int* ctrB = (unsigned int*)(MiB + 655360);
    unsigned short* otwH = (unsigned short*)(MiB + 786432);

    hipMemsetAsync(ctrB, 0, 64 * MAX_ITER * sizeof(unsigned int), stream);

    // -1) otw -> fp16 (tiny)
    cvt_f16<<<dim3(256), 256, 0, stream>>>(otw, otwH);

    // 1) fused K-GEMM + colmax + exp + xT producer
    gemm1_exp<<<dim3(64, 1, 8), 256, 0, stream>>>(otwH, x, ekb, MiB, xT);

    // 2) Sinkhorn v8 (6 barriers/iter) -> T fp16 over ek
    sinkhorn_split<<<dim3(64, 1, 4), 1024, 0, stream>>>(ekb, MiB, xchg, ctrB);

    // 3) feat = T . xT^T: NF=2, grid (64,1,16) = 4 blocks/CU, HMAP
    mfma_gemm<false, 1, 2, true, true><<<dim3(64, 1, 16), 256, 0, stream>>>(
        ekb, xT, nullptr, feat,
        1024, 1024, 1024, 1024, 4,
        0, 131072, 1048576, 0, 0, 131072, 1.0f);

    // 4) split-K x4 GEMM3 -> fp16 partials (CMODE 1)
    mfma_gemm<true, 1, 2, false, false><<<dim3(16, 1, 64), 256, 0, stream>>>(
        feat, lin_w, nullptr, partial,
        1024, 1024, 4096, 1024, 16,
        131072, 524288, 1024, 0, 2097152, 131072, 1.0f);

    // 5) out = relu(sum_ks partial + bias)
    splitk_reduce<<<dim3(1024), 256, 0, stream>>>(partial, lin_b, out);
}